// Round 9
// baseline (2678.336 us; speedup 1.0000x reference)
//
#include <hip/hip_runtime.h>

#define BB 64
#define TT 1024
#define DD 256
#define HH 256
#define CH 8             // timesteps per LDS chunk
#define NCH (TT / CH)    // 128 chunks

typedef float vf4 __attribute__((ext_vector_type(4)));
typedef float vf2 __attribute__((ext_vector_type(2)));
struct alignas(16) v2x2 { vf2 lo, hi; };   // one 16-B load, two pk-operands

#define LD4(p) (*(const vf4*)(p))
#define LDW(p) (*(const v2x2*)(p))

// tanh(x) = 1 - 2/(e^{2x}+1); saturates correctly for large |x|.
__device__ __forceinline__ float fast_tanh(float x) {
    float e = __expf(2.0f * x);
    return 1.0f - 2.0f / (e + 1.0f);
}

// Strict-VGPR packed FMA/MUL via inline asm (R9 proved gfx950 VALU cannot
// source AGPRs; these keep a hard VGPR requirement at every use site).
#define APKMUL(acc, ww, hh) \
    asm("v_pk_mul_f32 %0, %1, %2" : "=v"(acc) : "v"(ww), "v"(hh))
#define APKFMA(acc, ww, hh) \
    asm("v_pk_fma_f32 %0, %1, %2, %0" : "+v"(acc) : "v"(ww), "v"(hh))

// dst = src + dpp_shuffle(src). VALU-pipe cross-lane (no LDS traffic).
// CTRL: 0xB1 quad_perm xor1, 0x4E quad_perm xor2, 0x124 row_ror:4, 0x128 row_ror:8.
#define DPPADD(dst, src, CTRL) {                                                   \
    int _di = __builtin_amdgcn_update_dpp(0, __float_as_int(src), CTRL, 0xF, 0xF, true); \
    dst = (src) + __int_as_float(_di); }

// NOTE: macro params must NOT be named x/y/z/w (component-accessor capture).
#define FMR(rr, bb, ss)                   \
    rr.x = fmaf((ss), (bb).x, rr.x);      \
    rr.y = fmaf((ss), (bb).y, rr.y);      \
    rr.z = fmaf((ss), (bb).z, rr.z);      \
    rr.w = fmaf((ss), (bb).w, rr.w)

// ---------------------------------------------------------------------------
// Phase 1 (unchanged, ~160 us): xp = x * W_ih^T + b_ih, tiled GEMM.
// ---------------------------------------------------------------------------
#define BKb 32
#define LDP 132

__global__ __attribute__((amdgpu_flat_work_group_size(256, 256),
                          amdgpu_waves_per_eu(4, 4)))
void xproj_kernel(const float* __restrict__ x, const float* __restrict__ W_ih,
                  const float* __restrict__ b_ih, float* __restrict__ xp)
{
    __shared__ float As[BKb][LDP];
    __shared__ float Bs[BKb][LDP];

    const int tid = threadIdx.x;
    const int nb = blockIdx.x & 1;
    const int mb = blockIdx.x >> 1;
    const int m0 = mb * 128;
    const int n0 = nb * 128;

    const int sr = tid >> 3;
    const int sk = (tid & 7) * 4;

    const int tx = tid & 15;
    const int ty = tid >> 4;
    const int ma = ty * 4, mh = 64 + ty * 4;
    const int na = tx * 4, nh = 64 + tx * 4;

    vf4 ra0 = 0, ra1 = 0, ra2 = 0, ra3 = 0, ra4 = 0, ra5 = 0, ra6 = 0, ra7 = 0;
    vf4 rb0 = 0, rb1 = 0, rb2 = 0, rb3 = 0, rb4 = 0, rb5 = 0, rb6 = 0, rb7 = 0;

    for (int k0 = 0; k0 < DD; k0 += BKb) {
        #pragma unroll
        for (int g = 0; g < 4; ++g) {
            const int r = sr + g * 32;
            const vf4 v = LD4(x + (size_t)(m0 + r) * DD + k0 + sk);
            As[sk + 0][r] = v.x; As[sk + 1][r] = v.y;
            As[sk + 2][r] = v.z; As[sk + 3][r] = v.w;
        }
        #pragma unroll
        for (int g = 0; g < 4; ++g) {
            const int n = sr + g * 32;
            const vf4 v = LD4(W_ih + (size_t)(n0 + n) * DD + k0 + sk);
            Bs[sk + 0][n] = v.x; Bs[sk + 1][n] = v.y;
            Bs[sk + 2][n] = v.z; Bs[sk + 3][n] = v.w;
        }
        __syncthreads();

        #pragma unroll
        for (int kk = 0; kk < BKb; ++kk) {
            const vf4 alo = LD4(&As[kk][ma]);
            const vf4 ahi = LD4(&As[kk][mh]);
            const vf4 bl  = LD4(&Bs[kk][na]);
            const vf4 bh  = LD4(&Bs[kk][nh]);
            FMR(ra0, bl, alo.x); FMR(rb0, bh, alo.x);
            FMR(ra1, bl, alo.y); FMR(rb1, bh, alo.y);
            FMR(ra2, bl, alo.z); FMR(rb2, bh, alo.z);
            FMR(ra3, bl, alo.w); FMR(rb3, bh, alo.w);
            FMR(ra4, bl, ahi.x); FMR(rb4, bh, ahi.x);
            FMR(ra5, bl, ahi.y); FMR(rb5, bh, ahi.y);
            FMR(ra6, bl, ahi.z); FMR(rb6, bh, ahi.z);
            FMR(ra7, bl, ahi.w); FMR(rb7, bh, ahi.w);
        }
        __syncthreads();
    }

    const vf4 bia = LD4(b_ih + n0 + na);
    const vf4 bib = LD4(b_ih + n0 + nh);

    #define STORE_ROW(m, rA, rB)                                   \
        {                                                          \
            float* outp = xp + (size_t)(m0 + (m)) * HH + n0;       \
            *(vf4*)(outp + na) = rA + bia;                         \
            *(vf4*)(outp + nh) = rB + bib;                         \
        }
    STORE_ROW(ma + 0, ra0, rb0); STORE_ROW(ma + 1, ra1, rb1);
    STORE_ROW(ma + 2, ra2, rb2); STORE_ROW(ma + 3, ra3, rb3);
    STORE_ROW(mh + 0, ra4, rb4); STORE_ROW(mh + 1, ra5, rb5);
    STORE_ROW(mh + 2, ra6, rb6); STORE_ROW(mh + 3, ra7, rb7);
    #undef STORE_ROW
}

// ---------------------------------------------------------------------------
// Phase 2: recurrence, one WG per batch (64 WGs). RESTRUCTURED to 256
// threads (4 waves, 1 wave/SIMD), G=16 outputs/lane x L=16 k-elems/lane,
// waves_per_eu(1,1) => 512-VGPR budget/wave.
// Rationale (R7-R10 evidence): at 256-reg budget the allocator ALWAYS parks
// the weights in AGPRs (VGPR_Count=88 across 4 coaxing attempts) and pays
// ~1 v_accvgpr_read per weight per use (VALU-dynamic ~2x static). gfx950
// VALU cannot source AGPRs (R9 compile proof), so the only fix is a budget
// where weights CAN'T be pressure-evicted: 256 weights + ~100 working set
// = ~350 < 512. Per-SIMD issue/step: 1 wave x ~230 instr x 2cyc = ~460 cyc
// vs previous 2 waves x 231 x 2 = 924 (half of which was copy churn).
// Reduction tree gains one level; all 256 lanes finalize exactly one
// output (jmine = jg*16 + c) -- no divergent writer guard.
// ---------------------------------------------------------------------------
__global__ __attribute__((amdgpu_flat_work_group_size(256, 256),
                          amdgpu_waves_per_eu(1, 1)))
void rnn_kernel(const float* __restrict__ W_hh, const float* __restrict__ b_hh,
                const float* __restrict__ xpin, float* __restrict__ hout)
{
    const int tid = threadIdx.x;
    const int jg = tid >> 4;          // 0..15: group of 16 outputs
    const int c  = tid & 15;          // 0..15: k-chunk (16 floats)
    const int j0 = jg * 16;
    const int jmine = j0 + c;         // the output this lane finalizes
    const int b = blockIdx.x;

    __shared__ float hbuf[2][16 * 20];     // h[k] at word (k>>4)*20 + (k&15)
    __shared__ float xchk[2][CH * HH];     // xp chunk double-buffer (2 x 8 KB)
    __shared__ float obuf[2][CH * HH];     // output staging double-buffer (2 x 8 KB)

    // Weights: 16 rows (j0..j0+15) x 16 cols (c*16..c*16+15) = 256 floats/lane.
    v2x2 w[16][4];
    #pragma unroll
    for (int r = 0; r < 16; ++r) {
        const float* wr = W_hh + (size_t)(j0 + r) * HH + c * 16;
        w[r][0] = LDW(wr + 0);  w[r][1] = LDW(wr + 4);
        w[r][2] = LDW(wr + 8);  w[r][3] = LDW(wr + 12);
    }
    const float bias = b_hh[jmine];

    // Pin weights ONCE (opaque redefinition => loads cannot be
    // rematerialized/sunk into the loop).
    #define PINROW2(r0, r1) \
        asm volatile("" : "+v"(w[r0][0].lo), "+v"(w[r0][0].hi), "+v"(w[r0][1].lo), "+v"(w[r0][1].hi), \
                          "+v"(w[r0][2].lo), "+v"(w[r0][2].hi), "+v"(w[r0][3].lo), "+v"(w[r0][3].hi), \
                          "+v"(w[r1][0].lo), "+v"(w[r1][0].hi), "+v"(w[r1][1].lo), "+v"(w[r1][1].hi), \
                          "+v"(w[r1][2].lo), "+v"(w[r1][2].hi), "+v"(w[r1][3].lo), "+v"(w[r1][3].hi))
    PINROW2(0, 1);  PINROW2(2, 3);  PINROW2(4, 5);  PINROW2(6, 7);
    PINROW2(8, 9);  PINROW2(10, 11); PINROW2(12, 13); PINROW2(14, 15);
    #undef PINROW2

    const float* xbase = xpin + (size_t)b * TT * HH;
    float*       obase = hout + (size_t)b * TT * HH;
    const int haddr = jg * 20 + c;          // LDS slot for jmine

    // ---- prologue: chunk 0 into LDS, chunk 1 into registers (in flight) ----
    vf4 rpf0 = LD4(xbase + tid * 8);              // chunk 0 (2048 floats, 8/thread)
    vf4 rpf1 = LD4(xbase + tid * 8 + 4);
    hbuf[0][tid] = 0.0f;                          // h_0 = 0 (320 words incl. pads)
    if (tid < 64) hbuf[0][256 + tid] = 0.0f;
    *(vf4*)&xchk[0][tid * 8]     = rpf0;          // (compiler inserts vmcnt wait)
    *(vf4*)&xchk[0][tid * 8 + 4] = rpf1;
    rpf0 = LD4(xbase + CH * HH + tid * 8);        // chunk 1, stays in flight
    rpf1 = LD4(xbase + CH * HH + tid * 8 + 4);
    __syncthreads();

    for (int ci = 0; ci < NCH; ++ci) {
        const int cb = ci & 1;

        const float* xc = &xchk[cb][0];
        float*       ob = &obuf[cb][0];

        // unroll 2: hbuf[s&1] parity compile-time, modest pressure.
        #pragma unroll 2
        for (int s = 0; s < CH; ++s) {
            // xp for this step: LDS read.
            const float xpb = xc[s * HH + jmine] + bias;

            const float* hc = &hbuf[s & 1][c * 20];
            const v2x2 h0 = LDW(hc + 0), h1 = LDW(hc + 4),
                       h2 = LDW(hc + 8), h3 = LDW(hc + 12);

            vf2 aa[16];
            #pragma unroll
            for (int r = 0; r < 16; ++r) {
                APKMUL(aa[r], w[r][0].lo, h0.lo);
                APKFMA(aa[r], w[r][0].hi, h0.hi);
                APKFMA(aa[r], w[r][1].lo, h1.lo);
                APKFMA(aa[r], w[r][1].hi, h1.hi);
                APKFMA(aa[r], w[r][2].lo, h2.lo);
                APKFMA(aa[r], w[r][2].hi, h2.hi);
                APKFMA(aa[r], w[r][3].lo, h3.lo);
                APKFMA(aa[r], w[r][3].hi, h3.hi);
            }

            float sv[16];
            #pragma unroll
            for (int i = 0; i < 16; ++i) sv[i] = aa[i].x + aa[i].y;

            // 16-lane reduce of 16 outputs:
            // xor1 +sel(c&1), xor2 +sel(c&2), ror4 +sel(c&4), ror8 +sel(c&8).
            // Lane c ends with the full 256-term sum for output j0 + c.
            float tv[16];
            #pragma unroll
            for (int i = 0; i < 16; ++i) { DPPADD(tv[i], sv[i], 0xB1); }
            float pv[8];
            #pragma unroll
            for (int i = 0; i < 8; ++i) pv[i] = (c & 1) ? tv[2 * i + 1] : tv[2 * i];
            float uv[8];
            #pragma unroll
            for (int i = 0; i < 8; ++i) { DPPADD(uv[i], pv[i], 0x4E); }
            float vv[4];
            #pragma unroll
            for (int i = 0; i < 4; ++i) vv[i] = (c & 2) ? uv[2 * i + 1] : uv[2 * i];
            float qv[4];
            #pragma unroll
            for (int i = 0; i < 4; ++i) { DPPADD(qv[i], vv[i], 0x124); }
            float rv[2];
            #pragma unroll
            for (int i = 0; i < 2; ++i) rv[i] = (c & 4) ? qv[2 * i + 1] : qv[2 * i];
            float ev[2];
            #pragma unroll
            for (int i = 0; i < 2; ++i) { DPPADD(ev[i], rv[i], 0x128); }
            const float vfin = (c & 8) ? ev[1] : ev[0];

            // Stage next xp chunk into the other LDS buffer (once per chunk;
            // rpf was loaded ~8 steps ago, so the vmcnt wait here is free).
            if (s == CH - 1 && ci != NCH - 1) {
                *(vf4*)&xchk[cb ^ 1][tid * 8]     = rpf0;
                *(vf4*)&xchk[cb ^ 1][tid * 8 + 4] = rpf1;
            }

            const float hn = fast_tanh(vfin + xpb);
            hbuf[1 - (s & 1)][haddr] = hn;        // h for next step
            ob[s * HH + jmine] = hn;              // output staging (LDS)
            __syncthreads();
        }

        // ---- chunk boundary: flush outputs, prefetch chunk ci+2 ----
        // obuf[cb] is complete (post-barrier); next chunk writes obuf[cb^1],
        // so the flush read cannot race.
        const vf4 ov0 = *(const vf4*)&obuf[cb][tid * 8];
        const vf4 ov1 = *(const vf4*)&obuf[cb][tid * 8 + 4];
        float* op = obase + (size_t)ci * CH * HH + tid * 8;
        *(vf4*)(op)     = ov0;
        *(vf4*)(op + 4) = ov1;
        if (ci + 2 < NCH) {
            rpf0 = LD4(xbase + (size_t)(ci + 2) * CH * HH + tid * 8);
            rpf1 = LD4(xbase + (size_t)(ci + 2) * CH * HH + tid * 8 + 4);
        }
        // These globals drain at the next chunk's first barrier — once per
        // 8 steps, overlapped with step-0 compute (~50 cyc/step amortized).
    }
}

extern "C" void kernel_launch(void* const* d_in, const int* in_sizes, int n_in,
                              void* d_out, int out_size, void* d_ws, size_t ws_size,
                              hipStream_t stream) {
    const float* x    = (const float*)d_in[0];
    const float* W_ih = (const float*)d_in[1];
    const float* W_hh = (const float*)d_in[2];
    const float* b_ih = (const float*)d_in[3];
    const float* b_hh = (const float*)d_in[4];
    float* out = (float*)d_out;

    const size_t xp_bytes = (size_t)BB * TT * HH * sizeof(float);   // 64 MiB
    // Aliased fallback stays correct: xp chunk k is loaded (2 chunks ahead)
    // strictly before out chunk k is flushed.
    float* xp = (ws_size >= xp_bytes) ? (float*)d_ws : out;

    xproj_kernel<<<dim3(512 * 2), dim3(256), 0, stream>>>(x, W_ih, b_ih, xp);
    rnn_kernel<<<dim3(BB), dim3(256), 0, stream>>>(W_hh, b_hh, xp, out);
}

// Round 10
// 1235.879 us; speedup vs baseline: 2.1672x; 2.1672x over previous
//
#include <hip/hip_runtime.h>

#define BB 64
#define TT 1024
#define DD 256
#define HH 256
#define CH 8             // timesteps per LDS chunk
#define NCH (TT / CH)    // 128 chunks

typedef float vf4 __attribute__((ext_vector_type(4)));
typedef float f32x4 __attribute__((ext_vector_type(4)));
typedef short bf16x8 __attribute__((ext_vector_type(8)));   // 8 bf16 = 4 VGPRs

#define LD4(p) (*(const vf4*)(p))

// tanh(x) = 1 - 2/(e^{2x}+1); saturates correctly for large |x|.
__device__ __forceinline__ float fast_tanh(float x) {
    float e = __expf(2.0f * x);
    return 1.0f - 2.0f / (e + 1.0f);
}

// fp32 -> bf16 round-to-nearest-even (returns the 16-bit pattern).
__device__ __forceinline__ unsigned bf16rne(float f) {
    unsigned u = __float_as_uint(f);
    return (u + 0x7FFFu + ((u >> 16) & 1u)) >> 16;
}

// NOTE: macro params must NOT be named x/y/z/w (component-accessor capture).
#define FMR(rr, bb, ss)                   \
    rr.x = fmaf((ss), (bb).x, rr.x);      \
    rr.y = fmaf((ss), (bb).y, rr.y);      \
    rr.z = fmaf((ss), (bb).z, rr.z);      \
    rr.w = fmaf((ss), (bb).w, rr.w)

// ---------------------------------------------------------------------------
// Phase 1 (unchanged, ~160 us): xp = x * W_ih^T + b_ih, tiled GEMM.
// ---------------------------------------------------------------------------
#define BKb 32
#define LDP 132

__global__ __attribute__((amdgpu_flat_work_group_size(256, 256),
                          amdgpu_waves_per_eu(4, 4)))
void xproj_kernel(const float* __restrict__ x, const float* __restrict__ W_ih,
                  const float* __restrict__ b_ih, float* __restrict__ xp)
{
    __shared__ float As[BKb][LDP];
    __shared__ float Bs[BKb][LDP];

    const int tid = threadIdx.x;
    const int nb = blockIdx.x & 1;
    const int mb = blockIdx.x >> 1;
    const int m0 = mb * 128;
    const int n0 = nb * 128;

    const int sr = tid >> 3;
    const int sk = (tid & 7) * 4;

    const int tx = tid & 15;
    const int ty = tid >> 4;
    const int ma = ty * 4, mh = 64 + ty * 4;
    const int na = tx * 4, nh = 64 + tx * 4;

    vf4 ra0 = 0, ra1 = 0, ra2 = 0, ra3 = 0, ra4 = 0, ra5 = 0, ra6 = 0, ra7 = 0;
    vf4 rb0 = 0, rb1 = 0, rb2 = 0, rb3 = 0, rb4 = 0, rb5 = 0, rb6 = 0, rb7 = 0;

    for (int k0 = 0; k0 < DD; k0 += BKb) {
        #pragma unroll
        for (int g = 0; g < 4; ++g) {
            const int r = sr + g * 32;
            const vf4 v = LD4(x + (size_t)(m0 + r) * DD + k0 + sk);
            As[sk + 0][r] = v.x; As[sk + 1][r] = v.y;
            As[sk + 2][r] = v.z; As[sk + 3][r] = v.w;
        }
        #pragma unroll
        for (int g = 0; g < 4; ++g) {
            const int n = sr + g * 32;
            const vf4 v = LD4(W_ih + (size_t)(n0 + n) * DD + k0 + sk);
            Bs[sk + 0][n] = v.x; Bs[sk + 1][n] = v.y;
            Bs[sk + 2][n] = v.z; Bs[sk + 3][n] = v.w;
        }
        __syncthreads();

        #pragma unroll
        for (int kk = 0; kk < BKb; ++kk) {
            const vf4 alo = LD4(&As[kk][ma]);
            const vf4 ahi = LD4(&As[kk][mh]);
            const vf4 bl  = LD4(&Bs[kk][na]);
            const vf4 bh  = LD4(&Bs[kk][nh]);
            FMR(ra0, bl, alo.x); FMR(rb0, bh, alo.x);
            FMR(ra1, bl, alo.y); FMR(rb1, bh, alo.y);
            FMR(ra2, bl, alo.z); FMR(rb2, bh, alo.z);
            FMR(ra3, bl, alo.w); FMR(rb3, bh, alo.w);
            FMR(ra4, bl, ahi.x); FMR(rb4, bh, ahi.x);
            FMR(ra5, bl, ahi.y); FMR(rb5, bh, ahi.y);
            FMR(ra6, bl, ahi.z); FMR(rb6, bh, ahi.z);
            FMR(ra7, bl, ahi.w); FMR(rb7, bh, ahi.w);
        }
        __syncthreads();
    }

    const vf4 bia = LD4(b_ih + n0 + na);
    const vf4 bib = LD4(b_ih + n0 + nh);

    #define STORE_ROW(m, rA, rB)                                   \
        {                                                          \
            float* outp = xp + (size_t)(m0 + (m)) * HH + n0;       \
            *(vf4*)(outp + na) = rA + bia;                         \
            *(vf4*)(outp + nh) = rB + bib;                         \
        }
    STORE_ROW(ma + 0, ra0, rb0); STORE_ROW(ma + 1, ra1, rb1);
    STORE_ROW(ma + 2, ra2, rb2); STORE_ROW(ma + 3, ra3, rb3);
    STORE_ROW(mh + 0, ra4, rb4); STORE_ROW(mh + 1, ra5, rb5);
    STORE_ROW(mh + 2, ra6, rb6); STORE_ROW(mh + 3, ra7, rb7);
    #undef STORE_ROW
}

// ---------------------------------------------------------------------------
// Phase 2: recurrence via MFMA. One WG per batch (64 WGs, 512 thr, 8 waves).
// R7-R11 proved: GEMV weights always AGPR-park; VALU can't source AGPRs
// (R9 compile proof) => unavoidable copy per weight-use => 617us floor.
// MFMA *can* source AGPRs => parked W fragments are free.
//   D(16x256) = H @ W^T, M padded to 16 (rows 1-15 of H stay zero).
//   fp32 via bf16 3-product split: h=h1+h2, w=w1+w2 (RNE), D = h1w1+h2w1+h1w2
//   (omitted h2w2 <= 6e-5; fresh err ~1e-4/step, steady ~5e-4 << 3.9e-3 tol).
//   Per wave: 2 N-tiles x 8 K-steps x 3 products = 48 MFMA/step.
//   Per SIMD: 96 MFMA x ~5cyc = 480 (vs 924 VALU-issue in the GEMV).
//   No DPP tree (K-reduce is inside MFMA). Epilogue: lanes 0-15 only
//   (D row 0 lives in lanes 0-15, reg 0 -- m89 layout).
// Fragment layouts (16x16x32 bf16): A: row=lane&15, k=(lane>>4)*8+j (8 contig);
// B: col=lane&15, k=(lane>>4)*8+j (8 contig from W row n); D: col=lane&15,
// row=(lane>>4)*4+reg [m89].
// ---------------------------------------------------------------------------
#define HSTR 264   // H row stride in shorts (528B = 33*16: aligned, 2-way banks)

__global__ __attribute__((amdgpu_flat_work_group_size(512, 512),
                          amdgpu_waves_per_eu(2, 2)))
void rnn_kernel(const float* __restrict__ W_hh, const float* __restrict__ b_hh,
                const float* __restrict__ xpin, float* __restrict__ hout)
{
    const int tid  = threadIdx.x;
    const int lane = tid & 63;
    const int wid  = tid >> 6;        // 0..7: wave => N-tiles {2w, 2w+1}
    const int rrow = lane & 15;       // A row / B col / D col
    const int kgrp = lane >> 4;       // 0..3: k-group
    const int b    = blockIdx.x;

    // Hs[0..1] = {H1,H2} buffer A;  Hs[2..3] = {H1,H2} buffer B (ping-pong).
    __shared__ __align__(16) short Hs[4][16 * HSTR];    // 33792 B
    __shared__ __align__(16) float xchk[2][CH * HH];    // 16384 B
    __shared__ __align__(16) float obuf[CH * HH];       //  8192 B  (58368 total)

    // ---- W fragments: [nt-local][split][kk], 128 VGPRs worth -> AGPRs ----
    bf16x8 wf[2][2][8];
    #pragma unroll
    for (int t = 0; t < 2; ++t) {
        const int n = (wid * 2 + t) * 16 + rrow;
        #pragma unroll
        for (int kk = 0; kk < 8; ++kk) {
            const int k0 = kk * 32 + kgrp * 8;
            const float* wp = W_hh + (size_t)n * HH + k0;
            bf16x8 s1, s2;
            #pragma unroll
            for (int j = 0; j < 8; ++j) {
                const float f = wp[j];
                const unsigned r1 = bf16rne(f);
                const float f1 = __uint_as_float(r1 << 16);
                const unsigned r2 = bf16rne(f - f1);
                s1[j] = (short)r1;
                s2[j] = (short)r2;
            }
            wf[t][0][kk] = s1;
            wf[t][1][kk] = s2;
        }
    }
    const float bias0 = b_hh[wid * 32 + rrow];
    const float bias1 = b_hh[wid * 32 + 16 + rrow];

    const float* xbase = xpin + (size_t)b * TT * HH;
    float*       obase = hout + (size_t)b * TT * HH;

    // ---- prologue: zero H (h_0 = 0 and padding rows 1-15), stage xp ----
    vf4 rpf = LD4(xbase + tid * 4);               // chunk 0 (2048 floats)
    for (int i = tid; i < 4 * 16 * HSTR / 2; i += 512) ((int*)Hs)[i] = 0;
    *(vf4*)&xchk[0][tid * 4] = rpf;               // (compiler inserts vmcnt wait)
    rpf = LD4(xbase + CH * HH + tid * 4);         // chunk 1, stays in flight
    __syncthreads();

    for (int ci = 0; ci < NCH; ++ci) {
        const int cb = ci & 1;
        const float* xc = &xchk[cb][0];

        #pragma unroll 2
        for (int s = 0; s < CH; ++s) {
            const short* A1 = &Hs[(s & 1) * 2 + 0][0];
            const short* A2 = &Hs[(s & 1) * 2 + 1][0];
            short* N1 = &Hs[((s + 1) & 1) * 2 + 0][0];
            short* N2 = &Hs[((s + 1) & 1) * 2 + 1][0];

            f32x4 ac0 = {0.f, 0.f, 0.f, 0.f};
            f32x4 ac1 = {0.f, 0.f, 0.f, 0.f};

            #pragma unroll
            for (int kk = 0; kk < 8; ++kk) {
                const int k0 = kk * 32 + kgrp * 8;
                const bf16x8 a1 = *(const bf16x8*)&A1[rrow * HSTR + k0];
                const bf16x8 a2 = *(const bf16x8*)&A2[rrow * HSTR + k0];
                ac0 = __builtin_amdgcn_mfma_f32_16x16x32_bf16(a1, wf[0][0][kk], ac0, 0, 0, 0);
                ac1 = __builtin_amdgcn_mfma_f32_16x16x32_bf16(a1, wf[1][0][kk], ac1, 0, 0, 0);
                ac0 = __builtin_amdgcn_mfma_f32_16x16x32_bf16(a2, wf[0][0][kk], ac0, 0, 0, 0);
                ac1 = __builtin_amdgcn_mfma_f32_16x16x32_bf16(a2, wf[1][0][kk], ac1, 0, 0, 0);
                ac0 = __builtin_amdgcn_mfma_f32_16x16x32_bf16(a1, wf[0][1][kk], ac0, 0, 0, 0);
                ac1 = __builtin_amdgcn_mfma_f32_16x16x32_bf16(a1, wf[1][1][kk], ac1, 0, 0, 0);
            }

            // Stage next xp chunk (rpf loaded ~8 steps ago; vmcnt wait free).
            if (s == CH - 1 && ci != NCH - 1) {
                *(vf4*)&xchk[cb ^ 1][tid * 4] = rpf;
            }

            // Epilogue: D row 0 lives in lanes 0-15, acc element 0.
            if (lane < 16) {
                #pragma unroll
                for (int t = 0; t < 2; ++t) {
                    const int n = (wid * 2 + t) * 16 + lane;
                    const float acc = t ? ac1[0] : ac0[0];
                    const float v = acc + xc[s * HH + n] + (t ? bias1 : bias0);
                    const float hn = fast_tanh(v);
                    const unsigned r1 = bf16rne(hn);
                    const float h1f = __uint_as_float(r1 << 16);
                    const unsigned r2 = bf16rne(hn - h1f);
                    N1[n] = (short)r1;            // h1 for next step
                    N2[n] = (short)r2;            // h2 for next step
                    obuf[s * HH + n] = hn;        // fp32 output staging
                }
            }
            __syncthreads();
        }

        // ---- chunk boundary: flush outputs, prefetch chunk ci+2 ----
        const vf4 ov = *(const vf4*)&obuf[tid * 4];
        *(vf4*)(obase + (size_t)ci * CH * HH + tid * 4) = ov;
        if (ci + 2 < NCH) {
            rpf = LD4(xbase + (size_t)(ci + 2) * CH * HH + tid * 4);
        }
        // obuf is single-buffered: barrier so no wave starts writing the next
        // chunk's obuf before all waves finished the flush read.
        __syncthreads();
    }
}

extern "C" void kernel_launch(void* const* d_in, const int* in_sizes, int n_in,
                              void* d_out, int out_size, void* d_ws, size_t ws_size,
                              hipStream_t stream) {
    const float* x    = (const float*)d_in[0];
    const float* W_ih = (const float*)d_in[1];
    const float* W_hh = (const float*)d_in[2];
    const float* b_ih = (const float*)d_in[3];
    const float* b_hh = (const float*)d_in[4];
    float* out = (float*)d_out;

    const size_t xp_bytes = (size_t)BB * TT * HH * sizeof(float);   // 64 MiB
    // Aliased fallback stays correct: xp chunk k is loaded (2 chunks ahead)
    // strictly before out chunk k is flushed.
    float* xp = (ws_size >= xp_bytes) ? (float*)d_ws : out;

    xproj_kernel<<<dim3(512 * 2), dim3(256), 0, stream>>>(x, W_ih, b_ih, xp);
    rnn_kernel<<<dim3(BB), dim3(512), 0, stream>>>(W_hh, b_hh, xp, out);
}